// Round 3
// baseline (279.268 us; speedup 1.0000x reference)
//
#include <hip/hip_runtime.h>
#include <math.h>

#define NRREL 16
#define DDIM 128
#define BBATCH 4096
#define SNBR 64

typedef __attribute__((ext_vector_type(8))) short short8;
typedef __attribute__((ext_vector_type(4))) float floatx4;

__device__ __forceinline__ unsigned short f2bf(float f) {
    unsigned u = __builtin_bit_cast(unsigned, f);
    u += 0x7fffu + ((u >> 16) & 1u);
    return (unsigned short)(u >> 16);
}
__device__ __forceinline__ float bf2f(unsigned short u) {
    return __builtin_bit_cast(float, ((unsigned)u) << 16);
}

// ---------------- gather: node emb + per-relation weighted neighbor sums (bf16 out) ----
// 128 thr/block, 1 batch row per block. 4 row-groups x 32 lanes x float4 loads.
// 4 private LDS accumulator copies (one per row-group) -> no races, reduce at end.
extern "C" __global__ __launch_bounds__(128)
void k_gather(const int* __restrict__ drug, const int* __restrict__ adj_e,
              const int* __restrict__ adj_r, const float* __restrict__ ew,
              const float* __restrict__ emb,
              unsigned short* __restrict__ pre_bf,
              float* __restrict__ node_f, unsigned short* __restrict__ node_bf)
{
    const int b = blockIdx.x, t = threadIdx.x;
    const int g = t >> 5, c = t & 31;            // row-group, column-group (4 cols)
    __shared__ float pre4[4 * NRREL * DDIM];     // 32 KB
    #pragma unroll
    for (int i = t; i < 4 * NRREL * DDIM; i += 128) pre4[i] = 0.f;
    __syncthreads();

    const int base = b * SNBR;
    float* myacc = pre4 + g * (NRREL * DDIM) + 4 * c;
    #pragma unroll 4
    for (int i = 0; i < SNBR / 4; ++i) {
        int s = 4 * i + g;
        int e = adj_e[base + s];
        int r = adj_r[base + s];
        float w = ew[base + s];
        float4 v = *(const float4*)(emb + (size_t)e * DDIM + 4 * c);
        float* p = myacc + r * DDIM;
        p[0] = fmaf(v.x, w, p[0]);
        p[1] = fmaf(v.y, w, p[1]);
        p[2] = fmaf(v.z, w, p[2]);
        p[3] = fmaf(v.w, w, p[3]);
    }
    // node embedding (first 32 lanes, float4)
    if (t < 32) {
        float4 nf = *(const float4*)(emb + (size_t)drug[b] * DDIM + 4 * t);
        *(float4*)(node_f + (size_t)b * DDIM + 4 * t) = nf;
        ushort4 nb = { f2bf(nf.x), f2bf(nf.y), f2bf(nf.z), f2bf(nf.w) };
        *(ushort4*)(node_bf + (size_t)b * DDIM + 4 * t) = nb;
    }
    __syncthreads();
    #pragma unroll
    for (int idx = t; idx < NRREL * DDIM; idx += 128) {
        float v = pre4[idx] + pre4[2048 + idx] + pre4[4096 + idx] + pre4[6144 + idx];
        pre_bf[(size_t)b * 2048 + idx] = f2bf(v);
    }
}

// ---------------- weight convert (+ W_rgcn transpose to [N=256][K=2048]) ---------------
extern "C" __global__ __launch_bounds__(256)
void k_wconv(const float* __restrict__ W_rgcn, const float* __restrict__ res_w,
             const float* __restrict__ proj_w, const float* __restrict__ in_w,
             const float* __restrict__ out_w,
             unsigned short* __restrict__ Wcat, unsigned short* __restrict__ resw,
             unsigned short* __restrict__ projw, unsigned short* __restrict__ inw,
             unsigned short* __restrict__ outw)
{
    int i = blockIdx.x * 256 + threadIdx.x;
    if (i < 524288) {               // Wcat[n][k] = W_rgcn[l][k][e], n = l*128+e
        int n = i >> 11, k = i & 2047;
        int l = n >> 7, e = n & 127;
        Wcat[i] = f2bf(W_rgcn[((size_t)l * 2048 + k) * 128 + e]);
    } else {
        int j = i - 524288;
        if (j < 32768)       resw[j] = f2bf(res_w[j]);
        else if (j < 65536)  projw[j - 32768] = f2bf(proj_w[j - 32768]);
        else if (j < 114688) inw[j - 65536] = f2bf(in_w[j - 65536]);
        else                 outw[j - 114688] = f2bf(out_w[j - 114688]);
    }
}

// ---------------- msgs = pre x Wcat^T : [4096,2048]x[2048,256] ------------------------
extern "C" __global__ __launch_bounds__(256)
void k_msgs(const unsigned short* __restrict__ pre_bf,
            const unsigned short* __restrict__ Wcat, float* __restrict__ msgs)
{
    int wave = threadIdx.x >> 6, wm = wave >> 1, wn = wave & 1;
    int r0 = blockIdx.x * 64 + wm * 32;
    int c0 = blockIdx.y * 64 + wn * 32;
    int lane = threadIdx.x & 63, l15 = lane & 15, q = lane >> 4;
    floatx4 acc[2][2] = {};
    const unsigned short* a0 = pre_bf + (size_t)(r0 + l15) * 2048 + q * 8;
    const unsigned short* a1 = a0 + (size_t)16 * 2048;
    const unsigned short* b0 = Wcat + (size_t)(c0 + l15) * 2048 + q * 8;
    const unsigned short* b1 = b0 + (size_t)16 * 2048;
    #pragma unroll 2
    for (int k = 0; k < 2048; k += 32) {
        short8 A0 = *(const short8*)(a0 + k);
        short8 A1 = *(const short8*)(a1 + k);
        short8 B0 = *(const short8*)(b0 + k);
        short8 B1 = *(const short8*)(b1 + k);
        acc[0][0] = __builtin_amdgcn_mfma_f32_16x16x32_bf16(A0, B0, acc[0][0], 0, 0, 0);
        acc[0][1] = __builtin_amdgcn_mfma_f32_16x16x32_bf16(A0, B1, acc[0][1], 0, 0, 0);
        acc[1][0] = __builtin_amdgcn_mfma_f32_16x16x32_bf16(A1, B0, acc[1][0], 0, 0, 0);
        acc[1][1] = __builtin_amdgcn_mfma_f32_16x16x32_bf16(A1, B1, acc[1][1], 0, 0, 0);
    }
    for (int mi = 0; mi < 2; ++mi)
        for (int ni = 0; ni < 2; ++ni) {
            int gc = c0 + ni * 16 + l15;
            #pragma unroll
            for (int r = 0; r < 4; ++r) {
                int gr = r0 + mi * 16 + 4 * q + r;
                msgs[(size_t)gr * 256 + gc] = acc[mi][ni][r];
            }
        }
}

// ---------------- fused layer: h=relu(node+msgs+node*resw^T+rb); node=LN(h*projw^T+pb+node)
extern "C" __global__ __launch_bounds__(256)
void k_layer(const unsigned short* __restrict__ resw, const unsigned short* __restrict__ projw,
             const float* __restrict__ res_b, const float* __restrict__ proj_b,
             const float* __restrict__ ln_g, const float* __restrict__ ln_b,
             const float* __restrict__ msgs,
             float* __restrict__ node_f, unsigned short* __restrict__ node_bf,
             unsigned short* __restrict__ xs_bf, int l)
{
    __shared__ unsigned short h_lds[64][136];    // pad 128->136: A-frag reads 2-way only
    const int t = threadIdx.x, w = t >> 6, lane = t & 63, l15 = lane & 15, q = lane >> 4;
    const int r0 = blockIdx.x * 64;
    // ---- stage 1: h = relu(node + msgs_l + node x res_w_l^T + res_b) ----
    {
        const unsigned short* Rw = resw + (size_t)l * DDIM * DDIM;
        floatx4 acc[8] = {};
        const unsigned short* ap = node_bf + (size_t)(r0 + 16 * w + l15) * DDIM + 8 * q;
        #pragma unroll
        for (int kk = 0; kk < DDIM; kk += 32) {
            short8 A0 = *(const short8*)(ap + kk);
            #pragma unroll
            for (int ni = 0; ni < 8; ++ni) {
                short8 B = *(const short8*)(Rw + (size_t)(ni * 16 + l15) * DDIM + kk + 8 * q);
                acc[ni] = __builtin_amdgcn_mfma_f32_16x16x32_bf16(A0, B, acc[ni], 0, 0, 0);
            }
        }
        #pragma unroll
        for (int ni = 0; ni < 8; ++ni) {
            int gc = ni * 16 + l15;
            float rb = res_b[l * DDIM + gc];
            #pragma unroll
            for (int r = 0; r < 4; ++r) {
                int lr = 16 * w + 4 * q + r, gr = r0 + lr;
                float v = acc[ni][r] + rb + node_f[(size_t)gr * DDIM + gc]
                        + msgs[(size_t)gr * 256 + l * DDIM + gc];
                h_lds[lr][gc] = f2bf(v > 0.f ? v : 0.f);
            }
        }
    }
    __syncthreads();
    // ---- stage 2: node = LN(h x proj_w_l^T + proj_b + node) ----
    {
        const unsigned short* Pw = projw + (size_t)l * DDIM * DDIM;
        floatx4 acc[8] = {};
        const unsigned short* ap = &h_lds[16 * w + l15][8 * q];
        #pragma unroll
        for (int kk = 0; kk < DDIM; kk += 32) {
            short8 A0 = *(const short8*)(ap + kk);
            #pragma unroll
            for (int ni = 0; ni < 8; ++ni) {
                short8 B = *(const short8*)(Pw + (size_t)(ni * 16 + l15) * DDIM + kk + 8 * q);
                acc[ni] = __builtin_amdgcn_mfma_f32_16x16x32_bf16(A0, B, acc[ni], 0, 0, 0);
            }
        }
        float vv[4][8];
        float s[4] = {0, 0, 0, 0}, sq[4] = {0, 0, 0, 0};
        #pragma unroll
        for (int ni = 0; ni < 8; ++ni) {
            int gc = ni * 16 + l15;
            float pb = proj_b[l * DDIM + gc];
            #pragma unroll
            for (int r = 0; r < 4; ++r) {
                int gr = r0 + 16 * w + 4 * q + r;
                float v = acc[ni][r] + pb + node_f[(size_t)gr * DDIM + gc];
                vv[r][ni] = v; s[r] += v; sq[r] += v * v;
            }
        }
        #pragma unroll
        for (int r = 0; r < 4; ++r)
            #pragma unroll
            for (int off = 8; off >= 1; off >>= 1) {
                s[r] += __shfl_xor(s[r], off, 64);
                sq[r] += __shfl_xor(sq[r], off, 64);
            }
        #pragma unroll
        for (int ni = 0; ni < 8; ++ni) {
            int gc = ni * 16 + l15;
            float g = ln_g[l * DDIM + gc], bb = ln_b[l * DDIM + gc];
            #pragma unroll
            for (int r = 0; r < 4; ++r) {
                int gr = r0 + 16 * w + 4 * q + r;
                float mean = s[r] * (1.f / DDIM);
                float var = sq[r] * (1.f / DDIM) - mean * mean;
                float val = (vv[r][ni] - mean) * rsqrtf(var + 1e-5f) * g + bb;
                node_f[(size_t)gr * DDIM + gc] = val;
                unsigned short vb = f2bf(val);
                node_bf[(size_t)gr * DDIM + gc] = vb;
                xs_bf[(size_t)(2 * gr + l) * DDIM + gc] = vb;
            }
        }
    }
}

// ---------------- fused head: qkv -> attention -> out-proj -> mean -> final LN --------
// block = 32 batch rows (64 xs rows); qkv + o staged in LDS
extern "C" __global__ __launch_bounds__(256)
void k_head(const unsigned short* __restrict__ xs_bf, const unsigned short* __restrict__ inw,
            const float* __restrict__ in_b, const unsigned short* __restrict__ outw,
            const float* __restrict__ out_b, const float* __restrict__ fg,
            const float* __restrict__ fb, float* __restrict__ outp)
{
    __shared__ unsigned short qkv_lds[64][392];  // 64x384 bf16, padded
    __shared__ unsigned short o_lds[64][136];
    const int t = threadIdx.x, w = t >> 6, lane = t & 63, l15 = lane & 15, q = lane >> 4;
    const int r0 = blockIdx.x * 64;              // xs row base
    // ---- stage 1: qkv[64,384] = xs x in_w^T + in_b ----
    {
        floatx4 acc[24] = {};
        const unsigned short* ap = xs_bf + (size_t)(r0 + 16 * w + l15) * DDIM + 8 * q;
        #pragma unroll
        for (int kk = 0; kk < DDIM; kk += 32) {
            short8 A0 = *(const short8*)(ap + kk);
            #pragma unroll
            for (int ni = 0; ni < 24; ++ni) {
                short8 B = *(const short8*)(inw + (size_t)(ni * 16 + l15) * DDIM + kk + 8 * q);
                acc[ni] = __builtin_amdgcn_mfma_f32_16x16x32_bf16(A0, B, acc[ni], 0, 0, 0);
            }
        }
        #pragma unroll
        for (int ni = 0; ni < 24; ++ni) {
            int gc = ni * 16 + l15;
            float ib = in_b[gc];
            #pragma unroll
            for (int r = 0; r < 4; ++r)
                qkv_lds[16 * w + 4 * q + r][gc] = f2bf(acc[ni][r] + ib);
        }
    }
    __syncthreads();
    // ---- stage 2: attention per batch row; 8 lanes per row, head = 32 dims = 2 lanes --
    {
        int g = t >> 3, j = t & 7;               // local b, 16-dim chunk
        const unsigned short* row0 = qkv_lds[2 * g];
        const unsigned short* row1 = qkv_lds[2 * g + 1];
        float p00 = 0.f, p01 = 0.f, p10 = 0.f, p11 = 0.f;
        #pragma unroll
        for (int dd = 0; dd < 16; ++dd) {
            int d = 16 * j + dd;
            float q0 = bf2f(row0[d]), k0 = bf2f(row0[128 + d]);
            float q1 = bf2f(row1[d]), k1 = bf2f(row1[128 + d]);
            p00 = fmaf(q0, k0, p00); p01 = fmaf(q0, k1, p01);
            p10 = fmaf(q1, k0, p10); p11 = fmaf(q1, k1, p11);
        }
        p00 += __shfl_xor(p00, 1, 64); p01 += __shfl_xor(p01, 1, 64);
        p10 += __shfl_xor(p10, 1, 64); p11 += __shfl_xor(p11, 1, 64);
        const float sc = 0.17677669529663687f;   // 1/sqrt(32)
        p00 *= sc; p01 *= sc; p10 *= sc; p11 *= sc;
        float m0 = fmaxf(p00, p01), e00 = expf(p00 - m0), e01 = expf(p01 - m0);
        float i0 = 1.f / (e00 + e01);
        float m1 = fmaxf(p10, p11), e10 = expf(p10 - m1), e11 = expf(p11 - m1);
        float i1 = 1.f / (e10 + e11);
        #pragma unroll
        for (int dd = 0; dd < 16; ++dd) {
            int d = 16 * j + dd;
            float v0 = bf2f(row0[256 + d]), v1 = bf2f(row1[256 + d]);
            o_lds[2 * g][d]     = f2bf((e00 * v0 + e01 * v1) * i0);
            o_lds[2 * g + 1][d] = f2bf((e10 * v0 + e11 * v1) * i1);
        }
    }
    __syncthreads();
    // ---- stage 3: out-proj + mean over L + final LN ----
    {
        floatx4 acc[8] = {};
        const unsigned short* ap = &o_lds[16 * w + l15][8 * q];
        #pragma unroll
        for (int kk = 0; kk < DDIM; kk += 32) {
            short8 A0 = *(const short8*)(ap + kk);
            #pragma unroll
            for (int ni = 0; ni < 8; ++ni) {
                short8 B = *(const short8*)(outw + (size_t)(ni * 16 + l15) * DDIM + kk + 8 * q);
                acc[ni] = __builtin_amdgcn_mfma_f32_16x16x32_bf16(A0, B, acc[ni], 0, 0, 0);
            }
        }
        float av[2][8];
        float s[2] = {0, 0}, sq[2] = {0, 0};
        #pragma unroll
        for (int ni = 0; ni < 8; ++ni) {
            int gc = ni * 16 + l15;
            float ob = out_b[gc];
            #pragma unroll
            for (int rr = 0; rr < 2; ++rr) {
                float v = 0.5f * (acc[ni][2 * rr] + acc[ni][2 * rr + 1]) + ob;
                av[rr][ni] = v; s[rr] += v; sq[rr] += v * v;
            }
        }
        #pragma unroll
        for (int rr = 0; rr < 2; ++rr)
            #pragma unroll
            for (int off = 8; off >= 1; off >>= 1) {
                s[rr] += __shfl_xor(s[rr], off, 64);
                sq[rr] += __shfl_xor(sq[rr], off, 64);
            }
        #pragma unroll
        for (int ni = 0; ni < 8; ++ni) {
            int gc = ni * 16 + l15;
            float g = fg[gc], bb = fb[gc];
            #pragma unroll
            for (int rr = 0; rr < 2; ++rr) {
                int bg = blockIdx.x * 32 + 8 * w + 2 * q + rr;
                float mean = s[rr] * (1.f / DDIM);
                float var = sq[rr] * (1.f / DDIM) - mean * mean;
                outp[(size_t)bg * DDIM + gc] = (av[rr][ni] - mean) * rsqrtf(var + 1e-5f) * g + bb;
            }
        }
    }
}

extern "C" void kernel_launch(void* const* d_in, const int* in_sizes, int n_in,
                              void* d_out, int out_size, void* d_ws, size_t ws_size,
                              hipStream_t stream) {
    const int*   drug_idx = (const int*)d_in[0];
    const int*   adj_ent  = (const int*)d_in[1];
    const int*   adj_rel  = (const int*)d_in[2];
    const float* ew       = (const float*)d_in[3];
    const float* emb      = (const float*)d_in[4];
    const float* W_rgcn   = (const float*)d_in[5];
    const float* res_w    = (const float*)d_in[6];
    const float* res_b    = (const float*)d_in[7];
    const float* proj_w   = (const float*)d_in[8];
    const float* proj_b   = (const float*)d_in[9];
    const float* ln_g     = (const float*)d_in[10];
    const float* ln_b     = (const float*)d_in[11];
    const float* in_w     = (const float*)d_in[12];
    const float* in_b     = (const float*)d_in[13];
    const float* out_w    = (const float*)d_in[14];
    const float* out_b    = (const float*)d_in[15];
    const float* fg       = (const float*)d_in[16];
    const float* fb       = (const float*)d_in[17];
    float* outp = (float*)d_out;

    char* ws = (char*)d_ws;
    size_t off = 0;
    auto alloc = [&](size_t bytes) { size_t o = off; off = (off + bytes + 255) & ~(size_t)255; return o; };
    unsigned short* pre_bf  = (unsigned short*)(ws + alloc((size_t)BBATCH * 2048 * 2));
    float*          node_f  = (float*)         (ws + alloc((size_t)BBATCH * 128 * 4));
    unsigned short* node_bf = (unsigned short*)(ws + alloc((size_t)BBATCH * 128 * 2));
    unsigned short* xs_bf   = (unsigned short*)(ws + alloc((size_t)2 * BBATCH * 128 * 2));
    float*          msgs    = (float*)         (ws + alloc((size_t)BBATCH * 256 * 4));
    unsigned short* Wcat    = (unsigned short*)(ws + alloc((size_t)256 * 2048 * 2));
    unsigned short* resw    = (unsigned short*)(ws + alloc((size_t)2 * 128 * 128 * 2));
    unsigned short* projw   = (unsigned short*)(ws + alloc((size_t)2 * 128 * 128 * 2));
    unsigned short* inw     = (unsigned short*)(ws + alloc((size_t)384 * 128 * 2));
    unsigned short* outw    = (unsigned short*)(ws + alloc((size_t)128 * 128 * 2));

    hipLaunchKernelGGL(k_wconv, dim3(2560), dim3(256), 0, stream,
                       W_rgcn, res_w, proj_w, in_w, out_w, Wcat, resw, projw, inw, outw);
    hipLaunchKernelGGL(k_gather, dim3(BBATCH), dim3(128), 0, stream,
                       drug_idx, adj_ent, adj_rel, ew, emb, pre_bf, node_f, node_bf);
    hipLaunchKernelGGL(k_msgs, dim3(64, 4), dim3(256), 0, stream, pre_bf, Wcat, msgs);
    for (int l = 0; l < 2; ++l)
        hipLaunchKernelGGL(k_layer, dim3(64), dim3(256), 0, stream,
                           resw, projw, res_b, proj_b, ln_g, ln_b, msgs,
                           node_f, node_bf, xs_bf, l);
    hipLaunchKernelGGL(k_head, dim3(128), dim3(256), 0, stream,
                       xs_bf, inw, in_b, outw, out_b, fg, fb, outp);
}

// Round 4
// 267.347 us; speedup vs baseline: 1.0446x; 1.0446x over previous
//
#include <hip/hip_runtime.h>
#include <math.h>

#define NRREL 16
#define DDIM 128
#define BBATCH 4096
#define SNBR 64

typedef __attribute__((ext_vector_type(8))) short short8;
typedef __attribute__((ext_vector_type(4))) float floatx4;

__device__ __forceinline__ unsigned short f2bf(float f) {
    unsigned u = __builtin_bit_cast(unsigned, f);
    u += 0x7fffu + ((u >> 16) & 1u);
    return (unsigned short)(u >> 16);
}
__device__ __forceinline__ float bf2f(unsigned short u) {
    return __builtin_bit_cast(float, ((unsigned)u) << 16);
}

// ============ weight convert: Wcat transpose via LDS + flat converts ==================
extern "C" __global__ __launch_bounds__(256)
void k_wconv(const float* __restrict__ W_rgcn, const float* __restrict__ res_w,
             const float* __restrict__ proj_w, const float* __restrict__ in_w,
             const float* __restrict__ out_w,
             unsigned short* __restrict__ Wcat, unsigned short* __restrict__ resw,
             unsigned short* __restrict__ projw, unsigned short* __restrict__ inw,
             unsigned short* __restrict__ outw)
{
    const int bid = blockIdx.x, t = threadIdx.x;
    if (bid < 64) {
        // transpose one [64 k x 128 e] tile of W_rgcn[l] -> Wcat[n=l*128+e][k]
        __shared__ float tileT[128 * 65];
        const int l = bid >> 5, k0 = (bid & 31) * 64;
        #pragma unroll
        for (int i = 0; i < 8; ++i) {
            int flat = t + 256 * i;            // 64 k x 32 c
            int k = flat >> 5, c = flat & 31;
            float4 v = *(const float4*)(W_rgcn + ((size_t)(l * 2048 + k0 + k)) * 128 + 4 * c);
            tileT[(4 * c + 0) * 65 + k] = v.x;
            tileT[(4 * c + 1) * 65 + k] = v.y;
            tileT[(4 * c + 2) * 65 + k] = v.z;
            tileT[(4 * c + 3) * 65 + k] = v.w;
        }
        __syncthreads();
        const int e = t >> 1, half = t & 1;
        #pragma unroll
        for (int m = 0; m < 4; ++m) {
            int kk = 32 * half + 8 * m;
            short8 o;
            #pragma unroll
            for (int j = 0; j < 8; ++j) o[j] = (short)f2bf(tileT[e * 65 + kk + j]);
            *(short8*)(Wcat + ((size_t)(l * 128 + e)) * 2048 + k0 + kk) = o;
        }
    } else {
        int j4 = (bid - 64) * 1024 + t * 4;    // 131072 elems total
        const float* src; unsigned short* dst; int off;
        if (j4 < 32768)       { src = res_w;  dst = resw;  off = j4; }
        else if (j4 < 65536)  { src = proj_w; dst = projw; off = j4 - 32768; }
        else if (j4 < 114688) { src = in_w;   dst = inw;   off = j4 - 65536; }
        else                  { src = out_w;  dst = outw;  off = j4 - 114688; }
        float4 v = *(const float4*)(src + off);
        ushort4 o = { f2bf(v.x), f2bf(v.y), f2bf(v.z), f2bf(v.w) };
        *(ushort4*)(dst + off) = o;
    }
}

// ============ gather: stage 64 scaled rows in LDS, register relation-scan =============
extern "C" __global__ __launch_bounds__(256)
void k_gather(const int* __restrict__ drug, const int* __restrict__ adj_e,
              const int* __restrict__ adj_r, const float* __restrict__ ew,
              const float* __restrict__ emb,
              unsigned short* __restrict__ pre_bf, float* __restrict__ node_f)
{
    __shared__ float rows[64 * 132];
    __shared__ int   srel[64];
    __shared__ float swt[64];
    __shared__ int   sent[64];
    const int b = blockIdx.x, t = threadIdx.x;
    if (t < 64) {
        sent[t] = adj_e[b * SNBR + t];
        srel[t] = adj_r[b * SNBR + t];
        swt[t]  = ew[b * SNBR + t];
    }
    __syncthreads();
    #pragma unroll
    for (int i = 0; i < 8; ++i) {
        int flat = t + 256 * i;                // 64 rows x 32 col-groups
        int s = flat >> 5, c = flat & 31;
        float w = swt[s];
        float4 v = *(const float4*)(emb + (size_t)sent[s] * DDIM + 4 * c);
        float4 sv; sv.x = v.x * w; sv.y = v.y * w; sv.z = v.z * w; sv.w = v.w * w;
        *(float4*)(rows + s * 132 + 4 * c) = sv;
    }
    if (t < 32) {
        float4 nf = *(const float4*)(emb + (size_t)drug[b] * DDIM + 4 * t);
        *(float4*)(node_f + (size_t)b * DDIM + 4 * t) = nf;
    }
    __syncthreads();
    const int r = t >> 4, g = t & 15;          // relation, 8-col group
    float acc[8] = {0.f, 0.f, 0.f, 0.f, 0.f, 0.f, 0.f, 0.f};
    #pragma unroll 4
    for (int s = 0; s < SNBR; ++s) {
        if (srel[s] == r) {
            const float* p = rows + s * 132 + 8 * g;
            #pragma unroll
            for (int j = 0; j < 8; ++j) acc[j] += p[j];
        }
    }
    short8 o;
    #pragma unroll
    for (int j = 0; j < 8; ++j) o[j] = (short)f2bf(acc[j]);
    *(short8*)(pre_bf + (size_t)b * 2048 + r * DDIM + 8 * g) = o;
}

// ============ msgs partials: K-split x4, [4096,512]x[512,256] per chunk ===============
extern "C" __global__ __launch_bounds__(256)
void k_msgs(const unsigned short* __restrict__ pre_bf,
            const unsigned short* __restrict__ Wcat, float* __restrict__ part)
{
    const int wave = threadIdx.x >> 6, wm = wave >> 1, wn = wave & 1;
    const int r0 = blockIdx.x * 64 + wm * 32;
    const int c0 = blockIdx.y * 64 + wn * 32;
    const int koff = blockIdx.z * 512;
    const int lane = threadIdx.x & 63, l15 = lane & 15, q = lane >> 4;
    floatx4 acc[2][2] = {};
    const unsigned short* a0 = pre_bf + (size_t)(r0 + l15) * 2048 + koff + q * 8;
    const unsigned short* a1 = a0 + (size_t)16 * 2048;
    const unsigned short* b0 = Wcat + (size_t)(c0 + l15) * 2048 + koff + q * 8;
    const unsigned short* b1 = b0 + (size_t)16 * 2048;
    #pragma unroll 2
    for (int k = 0; k < 512; k += 32) {
        short8 A0 = *(const short8*)(a0 + k);
        short8 A1 = *(const short8*)(a1 + k);
        short8 B0 = *(const short8*)(b0 + k);
        short8 B1 = *(const short8*)(b1 + k);
        acc[0][0] = __builtin_amdgcn_mfma_f32_16x16x32_bf16(A0, B0, acc[0][0], 0, 0, 0);
        acc[0][1] = __builtin_amdgcn_mfma_f32_16x16x32_bf16(A0, B1, acc[0][1], 0, 0, 0);
        acc[1][0] = __builtin_amdgcn_mfma_f32_16x16x32_bf16(A1, B0, acc[1][0], 0, 0, 0);
        acc[1][1] = __builtin_amdgcn_mfma_f32_16x16x32_bf16(A1, B1, acc[1][1], 0, 0, 0);
    }
    float* dst = part + (size_t)blockIdx.z * BBATCH * 256;
    for (int mi = 0; mi < 2; ++mi)
        for (int ni = 0; ni < 2; ++ni) {
            int gc = c0 + ni * 16 + l15;
            #pragma unroll
            for (int r = 0; r < 4; ++r) {
                int gr = r0 + mi * 16 + 4 * q + r;
                dst[(size_t)gr * 256 + gc] = acc[mi][ni][r];
            }
        }
}

// ============ tail: layers (RGCN x2) + qkv + attention + out-proj + final LN ==========
// block = 32 batch rows, 256 threads, everything LDS-resident
extern "C" __global__ __launch_bounds__(256)
void k_tail(const float* __restrict__ node_fg, const float* __restrict__ part,
            const unsigned short* __restrict__ resw, const unsigned short* __restrict__ projw,
            const float* __restrict__ res_b, const float* __restrict__ proj_b,
            const float* __restrict__ ln_g, const float* __restrict__ ln_b,
            const unsigned short* __restrict__ inw, const float* __restrict__ in_b,
            const unsigned short* __restrict__ outw, const float* __restrict__ out_b,
            const float* __restrict__ fg, const float* __restrict__ fb,
            float* __restrict__ outp)
{
    __shared__ float          node_ln[32 * 132];
    __shared__ unsigned short node_b16[32 * 136];
    __shared__ unsigned short h_b16[32 * 136];
    __shared__ float          msum[32 * 260];
    __shared__ unsigned short xs_l[64 * 136];     // reused for o after qkv
    __shared__ unsigned short qkvl[64 * 392];
    __shared__ float          psum[2][32], psq[2][32];

    const int t = threadIdx.x, w = t >> 6, lane = t & 63, l15 = lane & 15, q = lane >> 4;
    const int r0 = blockIdx.x * 32;
    const int wm = w & 1, wn = w >> 1;

    // ---- stage 0: load node rows + reduce msgs partials ----
    #pragma unroll
    for (int i = 0; i < 4; ++i) {
        int flat = t + 256 * i;                  // 32 rows x 32 col4
        int rr = flat >> 5, c = flat & 31;
        float4 v = *(const float4*)(node_fg + (size_t)(r0 + rr) * DDIM + 4 * c);
        *(float4*)(node_ln + rr * 132 + 4 * c) = v;
        ushort4 o = { f2bf(v.x), f2bf(v.y), f2bf(v.z), f2bf(v.w) };
        *(ushort4*)(node_b16 + rr * 136 + 4 * c) = o;
    }
    #pragma unroll
    for (int i = 0; i < 8; ++i) {
        int flat = t + 256 * i;                  // 32 rows x 64 col4 (256 cols)
        int rr = flat >> 6, c = flat & 63;
        float4 s = {0.f, 0.f, 0.f, 0.f};
        #pragma unroll
        for (int kc = 0; kc < 4; ++kc) {
            float4 v = *(const float4*)(part + ((size_t)kc * BBATCH + r0 + rr) * 256 + 4 * c);
            s.x += v.x; s.y += v.y; s.z += v.z; s.w += v.w;
        }
        *(float4*)(msum + rr * 260 + 4 * c) = s;
    }
    __syncthreads();

    // ---- RGCN layers ----
    for (int l = 0; l < 2; ++l) {
        // GEMM1: h = relu(node + msum_l + node x resw_l^T + res_b); 16 rows x 64 cols/wave
        {
            const unsigned short* Bw = resw + (size_t)l * DDIM * DDIM;
            floatx4 acc[4] = {};
            const unsigned short* ap = node_b16 + (16 * wm + l15) * 136 + 8 * q;
            #pragma unroll
            for (int kk = 0; kk < DDIM; kk += 32) {
                short8 A = *(const short8*)(ap + kk);
                #pragma unroll
                for (int ni = 0; ni < 4; ++ni) {
                    short8 B = *(const short8*)(Bw + (size_t)(64 * wn + ni * 16 + l15) * DDIM + kk + 8 * q);
                    acc[ni] = __builtin_amdgcn_mfma_f32_16x16x32_bf16(A, B, acc[ni], 0, 0, 0);
                }
            }
            #pragma unroll
            for (int ni = 0; ni < 4; ++ni) {
                int gc = 64 * wn + ni * 16 + l15;
                float rb = res_b[l * DDIM + gc];
                #pragma unroll
                for (int r = 0; r < 4; ++r) {
                    int lr = 16 * wm + 4 * q + r;
                    float v = acc[ni][r] + rb + node_ln[lr * 132 + gc] + msum[lr * 260 + l * DDIM + gc];
                    h_b16[lr * 136 + gc] = f2bf(v > 0.f ? v : 0.f);
                }
            }
        }
        __syncthreads();
        // GEMM2 + LN: node = LN(h x projw_l^T + proj_b + node)
        {
            const unsigned short* Bw = projw + (size_t)l * DDIM * DDIM;
            floatx4 acc[4] = {};
            const unsigned short* ap = h_b16 + (16 * wm + l15) * 136 + 8 * q;
            #pragma unroll
            for (int kk = 0; kk < DDIM; kk += 32) {
                short8 A = *(const short8*)(ap + kk);
                #pragma unroll
                for (int ni = 0; ni < 4; ++ni) {
                    short8 B = *(const short8*)(Bw + (size_t)(64 * wn + ni * 16 + l15) * DDIM + kk + 8 * q);
                    acc[ni] = __builtin_amdgcn_mfma_f32_16x16x32_bf16(A, B, acc[ni], 0, 0, 0);
                }
            }
            float vv[4][4];
            float s4[4] = {0, 0, 0, 0}, sq4[4] = {0, 0, 0, 0};
            #pragma unroll
            for (int ni = 0; ni < 4; ++ni) {
                int gc = 64 * wn + ni * 16 + l15;
                float pb = proj_b[l * DDIM + gc];
                #pragma unroll
                for (int r = 0; r < 4; ++r) {
                    int lr = 16 * wm + 4 * q + r;
                    float v = acc[ni][r] + pb + node_ln[lr * 132 + gc];
                    vv[ni][r] = v; s4[r] += v; sq4[r] += v * v;
                }
            }
            #pragma unroll
            for (int r = 0; r < 4; ++r)
                #pragma unroll
                for (int off = 8; off >= 1; off >>= 1) {
                    s4[r] += __shfl_xor(s4[r], off, 64);
                    sq4[r] += __shfl_xor(sq4[r], off, 64);
                }
            if (l15 == 0) {
                #pragma unroll
                for (int r = 0; r < 4; ++r) {
                    psum[wn][16 * wm + 4 * q + r] = s4[r];
                    psq[wn][16 * wm + 4 * q + r] = sq4[r];
                }
            }
            __syncthreads();
            #pragma unroll
            for (int ni = 0; ni < 4; ++ni) {
                int gc = 64 * wn + ni * 16 + l15;
                float g = ln_g[l * DDIM + gc], bb = ln_b[l * DDIM + gc];
                #pragma unroll
                for (int r = 0; r < 4; ++r) {
                    int lr = 16 * wm + 4 * q + r;
                    float mean = (psum[0][lr] + psum[1][lr]) * (1.f / DDIM);
                    float var = (psq[0][lr] + psq[1][lr]) * (1.f / DDIM) - mean * mean;
                    float val = (vv[ni][r] - mean) * rsqrtf(var + 1e-5f) * g + bb;
                    node_ln[lr * 132 + gc] = val;
                    unsigned short ub = f2bf(val);
                    node_b16[lr * 136 + gc] = ub;
                    xs_l[(2 * lr + l) * 136 + gc] = ub;
                }
            }
            __syncthreads();
        }
    }

    // ---- qkv: wave w handles xs rows 16w..16w+15, all 384 cols ----
    {
        floatx4 acc[24] = {};
        const unsigned short* ap = xs_l + (16 * w + l15) * 136 + 8 * q;
        #pragma unroll
        for (int kk = 0; kk < DDIM; kk += 32) {
            short8 A = *(const short8*)(ap + kk);
            #pragma unroll
            for (int ni = 0; ni < 24; ++ni) {
                short8 B = *(const short8*)(inw + (size_t)(ni * 16 + l15) * DDIM + kk + 8 * q);
                acc[ni] = __builtin_amdgcn_mfma_f32_16x16x32_bf16(A, B, acc[ni], 0, 0, 0);
            }
        }
        #pragma unroll
        for (int ni = 0; ni < 24; ++ni) {
            int gc = ni * 16 + l15;
            float ib = in_b[gc];
            #pragma unroll
            for (int r = 0; r < 4; ++r)
                qkvl[(16 * w + 4 * q + r) * 392 + gc] = f2bf(acc[ni][r] + ib);
        }
    }
    __syncthreads();

    // ---- attention: per batch row pair; heads of 32 dims; 8 lanes/row ----
    {
        int g = t >> 3, j = t & 7;
        const unsigned short* row0 = qkvl + (2 * g) * 392;
        const unsigned short* row1 = qkvl + (2 * g + 1) * 392;
        float p00 = 0.f, p01 = 0.f, p10 = 0.f, p11 = 0.f;
        #pragma unroll
        for (int dd = 0; dd < 16; ++dd) {
            int d = 16 * j + dd;
            float q0 = bf2f(row0[d]), k0 = bf2f(row0[128 + d]);
            float q1 = bf2f(row1[d]), k1 = bf2f(row1[128 + d]);
            p00 = fmaf(q0, k0, p00); p01 = fmaf(q0, k1, p01);
            p10 = fmaf(q1, k0, p10); p11 = fmaf(q1, k1, p11);
        }
        p00 += __shfl_xor(p00, 1, 64); p01 += __shfl_xor(p01, 1, 64);
        p10 += __shfl_xor(p10, 1, 64); p11 += __shfl_xor(p11, 1, 64);
        const float sc = 0.17677669529663687f;   // 1/sqrt(32)
        p00 *= sc; p01 *= sc; p10 *= sc; p11 *= sc;
        float m0 = fmaxf(p00, p01), e00 = expf(p00 - m0), e01 = expf(p01 - m0);
        float i0 = 1.f / (e00 + e01);
        float m1 = fmaxf(p10, p11), e10 = expf(p10 - m1), e11 = expf(p11 - m1);
        float i1 = 1.f / (e10 + e11);
        #pragma unroll
        for (int dd = 0; dd < 16; ++dd) {
            int d = 16 * j + dd;
            float v0 = bf2f(row0[256 + d]), v1 = bf2f(row1[256 + d]);
            xs_l[(2 * g) * 136 + d]     = f2bf((e00 * v0 + e01 * v1) * i0);
            xs_l[(2 * g + 1) * 136 + d] = f2bf((e10 * v0 + e11 * v1) * i1);
        }
    }
    __syncthreads();

    // ---- out-proj + mean over L + final LN; wave w: o rows 16w..16w+15 ----
    {
        floatx4 acc[8] = {};
        const unsigned short* ap = xs_l + (16 * w + l15) * 136 + 8 * q;
        #pragma unroll
        for (int kk = 0; kk < DDIM; kk += 32) {
            short8 A = *(const short8*)(ap + kk);
            #pragma unroll
            for (int ni = 0; ni < 8; ++ni) {
                short8 B = *(const short8*)(outw + (size_t)(ni * 16 + l15) * DDIM + kk + 8 * q);
                acc[ni] = __builtin_amdgcn_mfma_f32_16x16x32_bf16(A, B, acc[ni], 0, 0, 0);
            }
        }
        float av[2][8];
        float s[2] = {0, 0}, sq[2] = {0, 0};
        #pragma unroll
        for (int ni = 0; ni < 8; ++ni) {
            int gc = ni * 16 + l15;
            float ob = out_b[gc];
            #pragma unroll
            for (int rr = 0; rr < 2; ++rr) {
                float v = 0.5f * (acc[ni][2 * rr] + acc[ni][2 * rr + 1]) + ob;
                av[rr][ni] = v; s[rr] += v; sq[rr] += v * v;
            }
        }
        #pragma unroll
        for (int rr = 0; rr < 2; ++rr)
            #pragma unroll
            for (int off = 8; off >= 1; off >>= 1) {
                s[rr] += __shfl_xor(s[rr], off, 64);
                sq[rr] += __shfl_xor(sq[rr], off, 64);
            }
        #pragma unroll
        for (int ni = 0; ni < 8; ++ni) {
            int gc = ni * 16 + l15;
            float g = fg[gc], bb = fb[gc];
            #pragma unroll
            for (int rr = 0; rr < 2; ++rr) {
                int bg = r0 + 8 * w + 2 * q + rr;
                float mean = s[rr] * (1.f / DDIM);
                float var = sq[rr] * (1.f / DDIM) - mean * mean;
                outp[(size_t)bg * DDIM + gc] = (av[rr][ni] - mean) * rsqrtf(var + 1e-5f) * g + bb;
            }
        }
    }
}

extern "C" void kernel_launch(void* const* d_in, const int* in_sizes, int n_in,
                              void* d_out, int out_size, void* d_ws, size_t ws_size,
                              hipStream_t stream) {
    const int*   drug_idx = (const int*)d_in[0];
    const int*   adj_ent  = (const int*)d_in[1];
    const int*   adj_rel  = (const int*)d_in[2];
    const float* ew       = (const float*)d_in[3];
    const float* emb      = (const float*)d_in[4];
    const float* W_rgcn   = (const float*)d_in[5];
    const float* res_w    = (const float*)d_in[6];
    const float* res_b    = (const float*)d_in[7];
    const float* proj_w   = (const float*)d_in[8];
    const float* proj_b   = (const float*)d_in[9];
    const float* ln_g     = (const float*)d_in[10];
    const float* ln_b     = (const float*)d_in[11];
    const float* in_w     = (const float*)d_in[12];
    const float* in_b     = (const float*)d_in[13];
    const float* out_w    = (const float*)d_in[14];
    const float* out_b    = (const float*)d_in[15];
    const float* fg       = (const float*)d_in[16];
    const float* fb       = (const float*)d_in[17];
    float* outp = (float*)d_out;

    char* ws = (char*)d_ws;
    size_t off = 0;
    auto alloc = [&](size_t bytes) { size_t o = off; off = (off + bytes + 255) & ~(size_t)255; return o; };
    unsigned short* pre_bf  = (unsigned short*)(ws + alloc((size_t)BBATCH * 2048 * 2));
    float*          node_f  = (float*)         (ws + alloc((size_t)BBATCH * 128 * 4));
    float*          part    = (float*)         (ws + alloc((size_t)4 * BBATCH * 256 * 4));
    unsigned short* Wcat    = (unsigned short*)(ws + alloc((size_t)256 * 2048 * 2));
    unsigned short* resw    = (unsigned short*)(ws + alloc((size_t)2 * 128 * 128 * 2));
    unsigned short* projw   = (unsigned short*)(ws + alloc((size_t)2 * 128 * 128 * 2));
    unsigned short* inw     = (unsigned short*)(ws + alloc((size_t)384 * 128 * 2));
    unsigned short* outw    = (unsigned short*)(ws + alloc((size_t)128 * 128 * 2));

    hipLaunchKernelGGL(k_wconv, dim3(192), dim3(256), 0, stream,
                       W_rgcn, res_w, proj_w, in_w, out_w, Wcat, resw, projw, inw, outw);
    hipLaunchKernelGGL(k_gather, dim3(BBATCH), dim3(256), 0, stream,
                       drug_idx, adj_ent, adj_rel, ew, emb, pre_bf, node_f);
    hipLaunchKernelGGL(k_msgs, dim3(64, 4, 4), dim3(256), 0, stream, pre_bf, Wcat, part);
    hipLaunchKernelGGL(k_tail, dim3(128), dim3(256), 0, stream,
                       node_f, part, resw, projw, res_b, proj_b, ln_g, ln_b,
                       inw, in_b, outw, out_b, fg, fb, outp);
}